// Round 12
// baseline (143.495 us; speedup 1.0000x reference)
//
#include <hip/hip_runtime.h>
#include <hip/hip_bf16.h>

// Problem constants
#define NUM_EXPERT 8
#define IN_FEAT    1024
#define HIDDEN_FEAT 4096
#define OUT_FEAT   1024
#define BATCH      2048

#define BM 128
#define BN 128
#define BKT 32        // K per step (one MFMA-K)
#define MAX_RBLK 24   // sum_e ceil(c_e/128) <= 16 + 8 = 24
#define KSPLIT2 4     // split-K factor for GEMM2

// ws layout (slack rows so unguarded A-tile loads stay in-bounds)
#define XG_ROWS   (BATCH + BM)
#define HDR_BYTES 16384
#define XG_BYTES  ((size_t)XG_ROWS * IN_FEAT * 2)
#define HID_BYTES ((size_t)XG_ROWS * HIDDEN_FEAT * 2)
#define PART_OFF  (HDR_BYTES + XG_BYTES + HID_BYTES)
#define PART_BYTES ((size_t)KSPLIT2 * BATCH * OUT_FEAT * 4)
#define WS_NEED   (PART_OFF + PART_BYTES)

typedef __attribute__((ext_vector_type(8))) short    bf16x8;
typedef __attribute__((ext_vector_type(4))) short    bf16x4;
typedef __attribute__((ext_vector_type(4))) float    f32x4;
typedef __attribute__((ext_vector_type(4))) unsigned u32x4;

#define GLOAD16(gp, lp)                                                        \
    __builtin_amdgcn_global_load_lds(                                          \
        (const __attribute__((address_space(1))) void*)(gp),                   \
        (__attribute__((address_space(3))) void*)(lp), 16, 0, 0)

__device__ inline short f2bf_rne(float f) {
    unsigned u = __builtin_bit_cast(unsigned, f);
    u += 0x7FFF + ((u >> 16) & 1);
    return (short)(u >> 16);
}

__device__ inline unsigned pk2(float a, float b) {
    unsigned ua = __builtin_bit_cast(unsigned, a);
    unsigned ub = __builtin_bit_cast(unsigned, b);
    ua += 0x7FFF + ((ua >> 16) & 1);
    ub += 0x7FFF + ((ub >> 16) & 1);
    return (ua >> 16) | (ub & 0xFFFF0000u);
}

// ---------------------------------------------------------------------------
// prep: histogram gate, scan, row-block table + permutation.
// hdr ints: [0]=n_blocks; [16+4i..]={expert,row_start,row_end}; [256..]=perm
// gate dtype probe: all odd int32 words zero -> int64 layout.
// ---------------------------------------------------------------------------
__global__ __launch_bounds__(256) void prep_kernel(const int* __restrict__ gate32,
                                                   int* __restrict__ hdr) {
    __shared__ int cnt[NUM_EXPERT];
    __shared__ int cur[NUM_EXPERT];
    __shared__ int odd_nonzero;
    int tid = threadIdx.x;
    if (tid < NUM_EXPERT) cnt[tid] = 0;
    if (tid == 0) odd_nonzero = 0;
    __syncthreads();

    int acc = 0;
    for (int t = tid; t < BATCH / 2; t += 256) acc |= gate32[2 * t + 1];
    if (acc) atomicOr(&odd_nonzero, 1);
    __syncthreads();
    const int is64 = (odd_nonzero == 0);

    for (int t = tid; t < BATCH; t += 256) {
        int g = is64 ? gate32[2 * t] : gate32[t];
        atomicAdd(&cnt[g], 1);
    }
    __syncthreads();
    if (tid == 0) {
        int o = 0, nb = 0;
        for (int e = 0; e < NUM_EXPERT; ++e) {
            cur[e] = o;
            int c = cnt[e];
            int rb = (c + BM - 1) / BM;
            for (int j = 0; j < rb; ++j) {
                hdr[16 + nb * 4 + 0] = e;
                hdr[16 + nb * 4 + 1] = o + j * BM;
                int re = o + j * BM + BM;
                if (re > o + c) re = o + c;
                hdr[16 + nb * 4 + 2] = re;
                ++nb;
            }
            o += c;
        }
        hdr[0] = nb;
    }
    __syncthreads();
    for (int t = tid; t < BATCH; t += 256) {
        int g = is64 ? gate32[2 * t] : gate32[t];
        int d = atomicAdd(&cur[g], 1);
        hdr[256 + d] = t;
    }
}

// ---------------------------------------------------------------------------
// gather: Xg[r][:] = bf16(inp[perm[r]][:])
// ---------------------------------------------------------------------------
__global__ __launch_bounds__(256) void gather_kernel(const float* __restrict__ inp,
                                                     const int* __restrict__ perm,
                                                     short* __restrict__ Xg) {
    int r = blockIdx.x;
    int t = perm[r];
    const f32x4* src = (const f32x4*)(inp + (size_t)t * IN_FEAT);
    f32x4 f = src[threadIdx.x];
    bf16x4 v;
    v[0] = f2bf_rne(f[0]); v[1] = f2bf_rne(f[1]);
    v[2] = f2bf_rne(f[2]); v[3] = f2bf_rne(f[3]);
    *(bf16x4*)(Xg + (size_t)r * IN_FEAT + threadIdx.x * 4) = v;
}

// ---------------------------------------------------------------------------
// MFMA GEMM, 128x128 tile, BKT=32, global_load_lds DOUBLE-buffer for BOTH
// operands (r6-G1 proven recipe), conflict-free layouts:
//   A bf16 pair-line (2 rows / 128B line, XOR j^(line&7))  -> 2-way = free
//   B fp32 chunk-XOR (8 chunks / 128B row,  XOR c^(row&7)) -> 2-way = free
// pk2->bf16 after ds_read (VALU, overlaps MFMA pipe). One barrier per step;
// stage issued BEFORE compute so DMA flies under MFMA; compiler-scheduled.
// MODE 0: bf16 store at gathered row. MODE 1: fp32 partial (z=blockIdx.z).
// MODE 2: fp32 scattered to Cf[perm[r]].  grid: (ntile, rblk, z)
// ---------------------------------------------------------------------------
template <int MODE, int KSPLIT>
__global__ __launch_bounds__(256) void gemm_kernel(
    const short* __restrict__ A, int lda,
    const float* __restrict__ W, int N, int K,
    short* __restrict__ Cbf, float* __restrict__ Cf, int ldc,
    const int* __restrict__ hdr) {

    __shared__ short As[2 * BM * BKT];        // 2 x 8 KB  (bf16)
    __shared__ float Bs[2 * BN * BKT];        // 2 x 16 KB (fp32)

    int nb = hdr[0];
    int ib = blockIdx.y;
    if (ib >= nb) return;
    int e  = hdr[16 + ib * 4 + 0];
    int rs = hdr[16 + ib * 4 + 1];
    int re = hdr[16 + ib * 4 + 2];
    const int* perm = hdr + 256;

    int n0 = blockIdx.x * BN;
    const float* Wb = W + (size_t)e * N * K;

    int tid  = threadIdx.x;
    int lane = tid & 63;
    int w    = tid >> 6;
    int wr   = w >> 1, wc = w & 1;            // 2x2 wave grid
    int lo   = lane & 15, hi = lane >> 4;

    const int kb = (KSPLIT > 1) ? (int)blockIdx.z * (K / KSPLIT) : 0;
    const int nt = (K / KSPLIT) / BKT;        // 32 for both GEMMs

    f32x4 acc[4][4];
#pragma unroll
    for (int m = 0; m < 4; ++m)
#pragma unroll
        for (int n = 0; n < 4; ++n) acc[m][n] = (f32x4){0.f, 0.f, 0.f, 0.f};

    // 6 gload issues per thread per stage; dest linear, source pre-swizzled
    auto stage = [&](int buf, int k0) {
#pragma unroll
        for (int i = 0; i < 2; ++i) {         // A: 512 slots of 16B, pair-line
            int s = i * 256 + tid;
            int line = s >> 3;
            int j = (s & 7) ^ (line & 7);
            int row = 2 * line + (j >> 2), c = j & 3;
            const short* gp = A + (size_t)(rs + row) * lda + k0 + c * 8;
            short* lp = As + buf * (BM * BKT) + (i * 256 + w * 64) * 8;
            GLOAD16(gp, lp);
        }
#pragma unroll
        for (int i = 0; i < 4; ++i) {         // B: 1024 slots of 16B, chunk-XOR
            int s = i * 256 + tid;
            int r = s >> 3, cs = s & 7;
            const float* gp = Wb + (size_t)(n0 + r) * K + k0 + ((cs ^ (r & 7)) * 4);
            float* lp = Bs + buf * (BN * BKT) + (i * 256 + w * 64) * 4;
            GLOAD16(gp, lp);
        }
    };

    auto compute = [&](int buf) {
        const short* Ab = As + buf * (BM * BKT);
        const float* Bb = Bs + buf * (BN * BKT);
        bf16x8 af[4], bfr[4];
#pragma unroll
        for (int m = 0; m < 4; ++m) {
            int row = wr * 64 + m * 16 + lo;
            int line = row >> 1;
            int j = ((row & 1) << 2) | hi;
            af[m] = *(const bf16x8*)(Ab + (line * 8 + (j ^ (line & 7))) * 8);
        }
#pragma unroll
        for (int n = 0; n < 4; ++n) {
            int r = wc * 64 + n * 16 + lo;
            f32x4 x = *(const f32x4*)(Bb + r * 32 + (((2 * hi)     ^ (r & 7)) * 4));
            f32x4 y = *(const f32x4*)(Bb + r * 32 + (((2 * hi + 1) ^ (r & 7)) * 4));
            u32x4 u;
            u[0] = pk2(x[0], x[1]); u[1] = pk2(x[2], x[3]);
            u[2] = pk2(y[0], y[1]); u[3] = pk2(y[2], y[3]);
            bfr[n] = __builtin_bit_cast(bf16x8, u);
        }
#pragma unroll
        for (int m = 0; m < 4; ++m)
#pragma unroll
            for (int n = 0; n < 4; ++n)
                acc[m][n] = __builtin_amdgcn_mfma_f32_16x16x32_bf16(
                    af[m], bfr[n], acc[m][n], 0, 0, 0);
    };

    stage(0, kb);
    __syncthreads();                          // buf0 ready
    for (int kt = 0; kt < nt; ++kt) {
        if (kt + 1 < nt) stage((kt + 1) & 1, kb + (kt + 1) * BKT); // under compute
        compute(kt & 1);
        __syncthreads();                      // drains DMA + read fence
    }

    // epilogue: D frag mapping col=lane&15, row=(lane>>4)*4+reg
#pragma unroll
    for (int m = 0; m < 4; ++m) {
#pragma unroll
        for (int rg = 0; rg < 4; ++rg) {
            int brow = wr * 64 + m * 16 + hi * 4 + rg;
            int grow = rs + brow;
            if (grow < re) {
                if constexpr (MODE == 0) {
                    short* dst = Cbf + (size_t)grow * ldc;
#pragma unroll
                    for (int n = 0; n < 4; ++n)
                        dst[n0 + wc * 64 + n * 16 + lo] = f2bf_rne(acc[m][n][rg]);
                } else if constexpr (MODE == 1) {
                    float* dst = Cf + (size_t)blockIdx.z * (BATCH * OUT_FEAT)
                                    + (size_t)grow * ldc;
#pragma unroll
                    for (int n = 0; n < 4; ++n)
                        dst[n0 + wc * 64 + n * 16 + lo] = acc[m][n][rg];
                } else {
                    int token = perm[grow];
                    float* dst = Cf + (size_t)token * ldc;
#pragma unroll
                    for (int n = 0; n < 4; ++n)
                        dst[n0 + wc * 64 + n * 16 + lo] = acc[m][n][rg];
                }
            }
        }
    }
}

// ---------------------------------------------------------------------------
// reduce split-K partials (fixed z order -> deterministic) + scatter to token
// ---------------------------------------------------------------------------
__global__ __launch_bounds__(256) void reduce_kernel(const float* __restrict__ part,
                                                     const int* __restrict__ perm,
                                                     float* __restrict__ out) {
    int r = blockIdx.x;
    const float* p = part + (size_t)r * OUT_FEAT + threadIdx.x * 4;
    f32x4 s = *(const f32x4*)p;
#pragma unroll
    for (int z = 1; z < KSPLIT2; ++z)
        s += *(const f32x4*)(p + (size_t)z * BATCH * OUT_FEAT);
    int token = perm[r];
    *(f32x4*)(out + (size_t)token * OUT_FEAT + threadIdx.x * 4) = s;
}

// ---------------------------------------------------------------------------
extern "C" void kernel_launch(void* const* d_in, const int* in_sizes, int n_in,
                              void* d_out, int out_size, void* d_ws, size_t ws_size,
                              hipStream_t stream) {
    const float* inp  = (const float*)d_in[0];
    const int*   gate = (const int*)d_in[1];
    const float* w1   = (const float*)d_in[2];
    const float* w2   = (const float*)d_in[3];
    float*       out  = (float*)d_out;

    int*   hdr  = (int*)d_ws;
    short* Xg   = (short*)((char*)d_ws + HDR_BYTES);
    short* Hid  = (short*)((char*)d_ws + HDR_BYTES + XG_BYTES);
    float* part = (float*)((char*)d_ws + PART_OFF);

    prep_kernel<<<1, 256, 0, stream>>>(gate, hdr);
    gather_kernel<<<BATCH, 256, 0, stream>>>(inp, hdr + 256, Xg);

    // GEMM1: [B,1024] x W1[e][4096,1024]^T -> Hid bf16 [B,4096]
    gemm_kernel<0, 1><<<dim3(HIDDEN_FEAT / BN, MAX_RBLK), 256, 0, stream>>>(
        Xg, IN_FEAT, w1, HIDDEN_FEAT, IN_FEAT, Hid, nullptr, HIDDEN_FEAT, hdr);

    if (ws_size >= WS_NEED) {
        // GEMM2 split-K=4: fp32 partials, then deterministic reduce + scatter
        gemm_kernel<1, KSPLIT2>
            <<<dim3(OUT_FEAT / BN, MAX_RBLK, KSPLIT2), 256, 0, stream>>>(
                Hid, HIDDEN_FEAT, w2, OUT_FEAT, HIDDEN_FEAT, nullptr, part,
                OUT_FEAT, hdr);
        reduce_kernel<<<BATCH, 256, 0, stream>>>(part, hdr + 256, out);
    } else {
        // fallback: direct scatter, no split
        gemm_kernel<2, 1><<<dim3(OUT_FEAT / BN, MAX_RBLK), 256, 0, stream>>>(
            Hid, HIDDEN_FEAT, w2, OUT_FEAT, HIDDEN_FEAT, nullptr, out,
            OUT_FEAT, hdr);
    }
}